// Round 1
// baseline (653.783 us; speedup 1.0000x reference)
//
#include <hip/hip_runtime.h>
#include <hip/hip_bf16.h>

#define DIN 256
#define DOUT 128

// ---------------- K0: zero degree + counts ----------------
__global__ void gcn_zero(float* __restrict__ deg, int* __restrict__ cnt, int N) {
    int i = blockIdx.x * blockDim.x + threadIdx.x;
    if (i < N) { deg[i] = 0.f; cnt[i] = 0; }
}

// ---------------- K1: accumulate degree (f32) + edge counts (int) ----------------
__global__ void gcn_count(const int* __restrict__ row, const float* __restrict__ vals,
                          float* __restrict__ deg, int* __restrict__ cnt, int E) {
    int e = blockIdx.x * blockDim.x + threadIdx.x;
    if (e < E) {
        int r = row[e];
        atomicAdd(&deg[r], vals[e]);
        atomicAdd(&cnt[r], 1);
    }
}

// ---------------- K2: deg -> d^{-1/2} in place ----------------
__global__ void gcn_dinv(float* __restrict__ deg, int N) {
    int i = blockIdx.x * blockDim.x + threadIdx.x;
    if (i < N) {
        float d = deg[i];
        deg[i] = (d > 0.f) ? rsqrtf(fmaxf(d, 1e-12f)) : 0.f;
    }
}

// ---------------- Scan (exclusive) of cnt -> row_ptr; chunk = 1024/block ----------------
__global__ void gcn_scan_partial(const int* __restrict__ cnt, int* __restrict__ blk, int N) {
    int b = blockIdx.x, t = threadIdx.x;
    int base = b * 1024 + t * 4;
    int s = 0;
#pragma unroll
    for (int k = 0; k < 4; ++k) { int i = base + k; if (i < N) s += cnt[i]; }
    for (int d = 32; d >= 1; d >>= 1) s += __shfl_down(s, d, 64);
    __shared__ int wsum[4];
    int lane = t & 63, wid = t >> 6;
    if (lane == 0) wsum[wid] = s;
    __syncthreads();
    if (t == 0) blk[b] = wsum[0] + wsum[1] + wsum[2] + wsum[3];
}

__global__ void gcn_scan_blk(int* __restrict__ blk, int nblk) {
    if (threadIdx.x == 0) {
        int run = 0;
        for (int i = 0; i < nblk; ++i) { int v = blk[i]; blk[i] = run; run += v; }
    }
}

__global__ void gcn_scan_final(const int* __restrict__ cnt, const int* __restrict__ blk,
                               int* __restrict__ row_ptr, int* __restrict__ cursor, int N, int E) {
    int b = blockIdx.x, t = threadIdx.x;
    int base = b * 1024 + t * 4;
    int v[4]; int s = 0;
#pragma unroll
    for (int k = 0; k < 4; ++k) { int i = base + k; v[k] = (i < N) ? cnt[i] : 0; s += v[k]; }
    int mysum = s;
    int lane = t & 63, wid = t >> 6;
    for (int d = 1; d < 64; d <<= 1) {
        int tt = __shfl_up(s, d, 64);
        if (lane >= d) s += tt;
    }
    __shared__ int wsum[4];
    if (lane == 63) wsum[wid] = s;
    __syncthreads();
    int woff = 0;
    for (int w = 0; w < wid; ++w) woff += wsum[w];
    int excl = blk[b] + woff + (s - mysum);
#pragma unroll
    for (int k = 0; k < 4; ++k) {
        int i = base + k;
        if (i < N) { row_ptr[i] = excl; cursor[i] = excl; }
        excl += v[k];
    }
    if (b == (int)gridDim.x - 1 && t == (int)blockDim.x - 1) row_ptr[N] = E;
}

// ---------------- K6: scatter edges into CSR order, fuse normalization ----------------
__global__ void gcn_fill(const int* __restrict__ row, const int* __restrict__ col,
                         const float* __restrict__ vals, const float* __restrict__ dinv,
                         int* __restrict__ cursor, int* __restrict__ csr_col,
                         float* __restrict__ csr_val, int E) {
    int e = blockIdx.x * blockDim.x + threadIdx.x;
    if (e < E) {
        int r = row[e], c = col[e];
        int p = atomicAdd(&cursor[r], 1);
        csr_col[p] = c;
        csr_val[p] = vals[e] * dinv[r] * dinv[c];
    }
}

// ---------------- K7: support = x @ W + b  (f32, LDS-tiled) ----------------
// block = 256 threads, tile = 32 nodes x 128 outputs, K tiled by 64
__global__ __launch_bounds__(256) void gcn_gemm(const float* __restrict__ x,
                                                const float* __restrict__ W,
                                                const float* __restrict__ bias,
                                                float* __restrict__ support, int N) {
    __shared__ float xs[32][64];
    __shared__ float wl[64 * 128];
    int t = threadIdx.x;
    int n0 = blockIdx.x * 32;
    int fo = (t & 31) * 4;        // 4 consecutive output features
    int ng = (t >> 5) * 4;        // 4 consecutive nodes within tile
    float acc[4][4] = {};
    for (int kt = 0; kt < DIN; kt += 64) {
        // stage x tile: 32 x 64 floats; each thread loads 8 contiguous floats
        {
            int n = t >> 3;
            int k = (t & 7) * 8;
            float4 a0 = make_float4(0, 0, 0, 0), a1 = a0;
            if (n0 + n < N) {
                const float* src = &x[(size_t)(n0 + n) * DIN + kt + k];
                a0 = *(const float4*)src;
                a1 = *(const float4*)(src + 4);
            }
            *(float4*)&xs[n][k] = a0;
            *(float4*)&xs[n][k + 4] = a1;
        }
        // stage W tile: 64 x 128 floats (contiguous block), 8 float4 per thread
        {
            const float4* Wv = (const float4*)&W[(size_t)kt * DOUT];
            float4* dst = (float4*)wl;
#pragma unroll
            for (int j = 0; j < 8; ++j) dst[t + j * 256] = Wv[t + j * 256];
        }
        __syncthreads();
#pragma unroll 4
        for (int k = 0; k < 64; ++k) {
            float4 wv = *(float4*)&wl[k * 128 + fo];
            float xa[4];
#pragma unroll
            for (int i = 0; i < 4; ++i) xa[i] = xs[ng + i][k];
#pragma unroll
            for (int i = 0; i < 4; ++i) {
                acc[i][0] += xa[i] * wv.x;
                acc[i][1] += xa[i] * wv.y;
                acc[i][2] += xa[i] * wv.z;
                acc[i][3] += xa[i] * wv.w;
            }
        }
        __syncthreads();
    }
    float4 bb = *(const float4*)&bias[fo];
#pragma unroll
    for (int i = 0; i < 4; ++i) {
        int n = n0 + ng + i;
        if (n < N) {
            float4 o;
            o.x = acc[i][0] + bb.x;
            o.y = acc[i][1] + bb.y;
            o.z = acc[i][2] + bb.z;
            o.w = acc[i][3] + bb.w;
            *(float4*)&support[(size_t)n * DOUT + fo] = o;
        }
    }
}

// ---------------- K8: out[r] = sum_j val[j] * support[col[j]]  (one wave per row) ----------------
__global__ __launch_bounds__(256) void gcn_spmm(const int* __restrict__ row_ptr,
                                                const int* __restrict__ csr_col,
                                                const float* __restrict__ csr_val,
                                                const float* __restrict__ support,
                                                float* __restrict__ out, int N) {
    int wid = threadIdx.x >> 6;
    int lane = threadIdx.x & 63;
    int r = blockIdx.x * 4 + wid;
    if (r >= N) return;
    int beg = row_ptr[r], end = row_ptr[r + 1];
    float2 acc = make_float2(0.f, 0.f);
    for (int j = beg; j < end; ++j) {
        int c = csr_col[j];
        float v = csr_val[j];
        float2 s = *(const float2*)&support[(size_t)c * DOUT + lane * 2];
        acc.x += v * s.x;
        acc.y += v * s.y;
    }
    *(float2*)&out[(size_t)r * DOUT + lane * 2] = acc;
}

extern "C" void kernel_launch(void* const* d_in, const int* in_sizes, int n_in,
                              void* d_out, int out_size, void* d_ws, size_t ws_size,
                              hipStream_t stream) {
    const float* x    = (const float*)d_in[0];
    const int*   row  = (const int*)d_in[1];
    const int*   col  = (const int*)d_in[2];
    const float* vals = (const float*)d_in[3];
    const float* W    = (const float*)d_in[4];
    const float* bias = (const float*)d_in[5];
    float* out = (float*)d_out;

    int N = in_sizes[0] / DIN;
    int E = in_sizes[1];
    int NBLK = (N + 1023) / 1024;

    // workspace layout (256B aligned)
    char* ws = (char*)d_ws;
    size_t off = 0;
    auto take = [&](size_t bytes) -> char* {
        char* p = ws + off;
        off = (off + bytes + 255) & ~(size_t)255;
        return p;
    };
    float* deg     = (float*)take((size_t)N * 4);          // becomes d^{-1/2}
    int*   cnt     = (int*)take((size_t)N * 4);
    int*   row_ptr = (int*)take((size_t)(N + 1) * 4);
    int*   cursor  = (int*)take((size_t)N * 4);
    int*   blk     = (int*)take((size_t)NBLK * 4);
    int*   csr_col = (int*)take((size_t)E * 4);
    float* csr_val = (float*)take((size_t)E * 4);
    float* support = (float*)take((size_t)N * DOUT * 4);
    (void)ws_size;

    int nbN = (N + 255) / 256;
    int nbE = (E + 255) / 256;

    gcn_zero<<<nbN, 256, 0, stream>>>(deg, cnt, N);
    gcn_count<<<nbE, 256, 0, stream>>>(row, vals, deg, cnt, E);
    gcn_dinv<<<nbN, 256, 0, stream>>>(deg, N);
    gcn_scan_partial<<<NBLK, 256, 0, stream>>>(cnt, blk, N);
    gcn_scan_blk<<<1, 64, 0, stream>>>(blk, NBLK);
    gcn_scan_final<<<NBLK, 256, 0, stream>>>(cnt, blk, row_ptr, cursor, N, E);
    gcn_fill<<<nbE, 256, 0, stream>>>(row, col, vals, deg, cursor, csr_col, csr_val, E);
    gcn_gemm<<<(N + 31) / 32, 256, 0, stream>>>(x, W, bias, support, N);
    gcn_spmm<<<(N + 3) / 4, 256, 0, stream>>>(row_ptr, csr_col, csr_val, support, out, N);
}

// Round 2
// 533.263 us; speedup vs baseline: 1.2260x; 1.2260x over previous
//
#include <hip/hip_runtime.h>
#include <hip/hip_bf16.h>

#define DIN 256
#define DOUT 128

typedef float f32x4 __attribute__((ext_vector_type(4)));
typedef __bf16 bf16x8 __attribute__((ext_vector_type(8)));
typedef unsigned short u16x8 __attribute__((ext_vector_type(8)));

__device__ __forceinline__ unsigned short f2bf(float f) {
    __bf16 h = (__bf16)f;
    return *(unsigned short*)&h;
}

// ---------------- K0: zero degree + counts ----------------
__global__ void gcn_zero(float* __restrict__ deg, int* __restrict__ cnt, int N) {
    int i = blockIdx.x * blockDim.x + threadIdx.x;
    if (i < N) { deg[i] = 0.f; cnt[i] = 0; }
}

// ---------------- K1: accumulate degree (f32) + edge counts (int) ----------------
__global__ void gcn_count(const int* __restrict__ row, const float* __restrict__ vals,
                          float* __restrict__ deg, int* __restrict__ cnt, int E) {
    int e = blockIdx.x * blockDim.x + threadIdx.x;
    if (e < E) {
        int r = row[e];
        atomicAdd(&deg[r], vals[e]);
        atomicAdd(&cnt[r], 1);
    }
}

// ---------------- K2: deg -> d^{-1/2} in place ----------------
__global__ void gcn_dinv(float* __restrict__ deg, int N) {
    int i = blockIdx.x * blockDim.x + threadIdx.x;
    if (i < N) {
        float d = deg[i];
        deg[i] = (d > 0.f) ? rsqrtf(fmaxf(d, 1e-12f)) : 0.f;
    }
}

// ---------------- exclusive scan of cnt -> row_ptr ----------------
__global__ void gcn_scan_partial(const int* __restrict__ cnt, int* __restrict__ blk, int N) {
    int b = blockIdx.x, t = threadIdx.x;
    int base = b * 1024 + t * 4;
    int s = 0;
#pragma unroll
    for (int k = 0; k < 4; ++k) { int i = base + k; if (i < N) s += cnt[i]; }
    for (int d = 32; d >= 1; d >>= 1) s += __shfl_down(s, d, 64);
    __shared__ int wsum[4];
    int lane = t & 63, wid = t >> 6;
    if (lane == 0) wsum[wid] = s;
    __syncthreads();
    if (t == 0) blk[b] = wsum[0] + wsum[1] + wsum[2] + wsum[3];
}

__global__ void gcn_scan_blk(int* __restrict__ blk, int nblk) {
    if (threadIdx.x == 0) {
        int run = 0;
        for (int i = 0; i < nblk; ++i) { int v = blk[i]; blk[i] = run; run += v; }
    }
}

__global__ void gcn_scan_final(const int* __restrict__ cnt, const int* __restrict__ blk,
                               int* __restrict__ row_ptr, int* __restrict__ cursor, int N, int E) {
    int b = blockIdx.x, t = threadIdx.x;
    int base = b * 1024 + t * 4;
    int v[4]; int s = 0;
#pragma unroll
    for (int k = 0; k < 4; ++k) { int i = base + k; v[k] = (i < N) ? cnt[i] : 0; s += v[k]; }
    int mysum = s;
    int lane = t & 63, wid = t >> 6;
    for (int d = 1; d < 64; d <<= 1) {
        int tt = __shfl_up(s, d, 64);
        if (lane >= d) s += tt;
    }
    __shared__ int wsum[4];
    if (lane == 63) wsum[wid] = s;
    __syncthreads();
    int woff = 0;
    for (int w = 0; w < wid; ++w) woff += wsum[w];
    int excl = blk[b] + woff + (s - mysum);
#pragma unroll
    for (int k = 0; k < 4; ++k) {
        int i = base + k;
        if (i < N) { row_ptr[i] = excl; cursor[i] = excl; }
        excl += v[k];
    }
    if (b == (int)gridDim.x - 1 && t == (int)blockDim.x - 1) row_ptr[N] = E;
}

// ---------------- fill CSR (packed col+val), fused normalization ----------------
__global__ void gcn_fill(const int* __restrict__ row, const int* __restrict__ col,
                         const float* __restrict__ vals, const float* __restrict__ dinv,
                         int* __restrict__ cursor, int2* __restrict__ csr, int E) {
    int e = blockIdx.x * blockDim.x + threadIdx.x;
    if (e < E) {
        int r = row[e], c = col[e];
        int p = atomicAdd(&cursor[r], 1);
        int2 pk;
        pk.x = c;
        pk.y = __float_as_int(vals[e] * dinv[r] * dinv[c]);
        csr[p] = pk;
    }
}

// ---------------- W f32 [256][128] -> Wt bf16 [128][256] ----------------
__global__ void gcn_wconv(const float* __restrict__ W, unsigned short* __restrict__ Wt) {
    int id = blockIdx.x * blockDim.x + threadIdx.x;  // 32768 total
    int c = id >> 8;       // 0..127
    int k = id & 255;      // 0..255
    Wt[c * 256 + k] = f2bf(W[k * DOUT + c]);
}

// ---------------- support = x @ W + b  (bf16 MFMA, tile 128x128, BK=64) ----------------
__global__ __launch_bounds__(256) void gcn_gemm(const float* __restrict__ x,
                                                const unsigned short* __restrict__ Wt,
                                                const float* __restrict__ bias,
                                                unsigned short* __restrict__ support, int N) {
    __shared__ unsigned short xs[128][72];   // x tile, bf16, padded stride 144B
    __shared__ unsigned short wl[128][72];   // Wt tile (col-major W), bf16

    int t = threadIdx.x;
    int n0 = blockIdx.x * 128;
    int l = t & 63;
    int w = t >> 6;           // wave 0..3; wave owns rows w*32..w*32+31
    int w32 = w * 32;
    int lr = l & 15;
    int lk = (l >> 4) * 8;

    f32x4 acc[2][8] = {};

    // staging roles
    int srow = t >> 1;            // 0..127
    int skk = (t & 1) * 32;       // 0 or 32

    for (int kt = 0; kt < DIN; kt += 64) {
        // stage x tile: row srow, k = kt+skk .. +31 (32 floats -> 32 bf16)
        {
            float4 f[8];
            if (n0 + srow < N) {
                const float4* src = (const float4*)&x[(size_t)(n0 + srow) * DIN + kt + skk];
#pragma unroll
                for (int i = 0; i < 8; ++i) f[i] = src[i];
            } else {
#pragma unroll
                for (int i = 0; i < 8; ++i) f[i] = make_float4(0, 0, 0, 0);
            }
#pragma unroll
            for (int i = 0; i < 4; ++i) {
                u16x8 pk;
                pk[0] = f2bf(f[2 * i].x);     pk[1] = f2bf(f[2 * i].y);
                pk[2] = f2bf(f[2 * i].z);     pk[3] = f2bf(f[2 * i].w);
                pk[4] = f2bf(f[2 * i + 1].x); pk[5] = f2bf(f[2 * i + 1].y);
                pk[6] = f2bf(f[2 * i + 1].z); pk[7] = f2bf(f[2 * i + 1].w);
                *(u16x8*)&xs[srow][skk + 8 * i] = pk;
            }
        }
        // stage Wt tile: col srow, k = kt+skk .. +31 (already bf16)
        {
            const u16x8* src = (const u16x8*)&Wt[(size_t)srow * DIN + kt + skk];
#pragma unroll
            for (int i = 0; i < 4; ++i) *(u16x8*)&wl[srow][skk + 8 * i] = src[i];
        }
        __syncthreads();
#pragma unroll
        for (int ks = 0; ks < 2; ++ks) {
            bf16x8 a[2], b[8];
#pragma unroll
            for (int m = 0; m < 2; ++m)
                a[m] = *(const bf16x8*)&xs[w32 + m * 16 + lr][ks * 32 + lk];
#pragma unroll
            for (int n = 0; n < 8; ++n)
                b[n] = *(const bf16x8*)&wl[n * 16 + lr][ks * 32 + lk];
#pragma unroll
            for (int m = 0; m < 2; ++m)
#pragma unroll
                for (int n = 0; n < 8; ++n)
                    acc[m][n] = __builtin_amdgcn_mfma_f32_16x16x32_bf16(a[m], b[n], acc[m][n], 0, 0, 0);
        }
        __syncthreads();
    }

    float bias_v[8];
#pragma unroll
    for (int n = 0; n < 8; ++n) bias_v[n] = bias[n * 16 + lr];

    int rbase = n0 + w32 + (l >> 4) * 4;
#pragma unroll
    for (int m = 0; m < 2; ++m) {
#pragma unroll
        for (int r = 0; r < 4; ++r) {
            int rowi = rbase + m * 16 + r;
            if (rowi < N) {
                unsigned short* dst = &support[(size_t)rowi * DOUT + lr];
#pragma unroll
                for (int n = 0; n < 8; ++n)
                    dst[n * 16] = f2bf(acc[m][n][r] + bias_v[n]);
            }
        }
    }
}

// ---------------- out[r] = sum_j val[j] * support_bf16[col[j]]  (one wave per row) ----------------
__global__ __launch_bounds__(256) void gcn_spmm(const int* __restrict__ row_ptr,
                                                const int2* __restrict__ csr,
                                                const unsigned short* __restrict__ support,
                                                float* __restrict__ out, int N) {
    int wid = threadIdx.x >> 6;
    int lane = threadIdx.x & 63;
    int r = blockIdx.x * 4 + wid;
    if (r >= N) return;
    int beg = row_ptr[r], end = row_ptr[r + 1];
    float accx = 0.f, accy = 0.f;

    int j = beg;
    int2 e;
    if (j < end) e = csr[j];
    while (j < end) {
        int c = e.x;
        float v = __int_as_float(e.y);
        ++j;
        if (j < end) e = csr[j];
        unsigned int p = *(const unsigned int*)&support[(size_t)c * DOUT + lane * 2];
        float slo = __uint_as_float(p << 16);
        float shi = __uint_as_float(p & 0xffff0000u);
        accx += v * slo;
        accy += v * shi;
    }
    float2 o; o.x = accx; o.y = accy;
    *(float2*)&out[(size_t)r * DOUT + lane * 2] = o;
}

extern "C" void kernel_launch(void* const* d_in, const int* in_sizes, int n_in,
                              void* d_out, int out_size, void* d_ws, size_t ws_size,
                              hipStream_t stream) {
    const float* x    = (const float*)d_in[0];
    const int*   row  = (const int*)d_in[1];
    const int*   col  = (const int*)d_in[2];
    const float* vals = (const float*)d_in[3];
    const float* W    = (const float*)d_in[4];
    const float* bias = (const float*)d_in[5];
    float* out = (float*)d_out;

    int N = in_sizes[0] / DIN;
    int E = in_sizes[1];
    int NBLK = (N + 1023) / 1024;

    char* ws = (char*)d_ws;
    size_t off = 0;
    auto take = [&](size_t bytes) -> char* {
        char* p = ws + off;
        off = (off + bytes + 255) & ~(size_t)255;
        return p;
    };
    float* deg     = (float*)take((size_t)N * 4);          // becomes d^{-1/2}
    int*   cnt     = (int*)take((size_t)N * 4);
    int*   row_ptr = (int*)take((size_t)(N + 1) * 4);
    int*   cursor  = (int*)take((size_t)N * 4);
    int*   blk     = (int*)take((size_t)NBLK * 4);
    int2*  csr     = (int2*)take((size_t)E * 8);
    unsigned short* Wt      = (unsigned short*)take((size_t)DIN * DOUT * 2);
    unsigned short* support = (unsigned short*)take((size_t)N * DOUT * 2);
    (void)ws_size;

    int nbN = (N + 255) / 256;
    int nbE = (E + 255) / 256;

    gcn_zero<<<nbN, 256, 0, stream>>>(deg, cnt, N);
    gcn_count<<<nbE, 256, 0, stream>>>(row, vals, deg, cnt, E);
    gcn_dinv<<<nbN, 256, 0, stream>>>(deg, N);
    gcn_scan_partial<<<NBLK, 256, 0, stream>>>(cnt, blk, N);
    gcn_scan_blk<<<1, 64, 0, stream>>>(blk, NBLK);
    gcn_scan_final<<<NBLK, 256, 0, stream>>>(cnt, blk, row_ptr, cursor, N, E);
    gcn_fill<<<nbE, 256, 0, stream>>>(row, col, vals, deg, cursor, csr, E);
    gcn_wconv<<<(DIN * DOUT) / 256, 256, 0, stream>>>(W, Wt);
    gcn_gemm<<<(N + 127) / 128, 256, 0, stream>>>(x, Wt, bias, support, N);
    gcn_spmm<<<(N + 3) / 4, 256, 0, stream>>>(row_ptr, csr, support, out, N);
}

// Round 3
// 453.201 us; speedup vs baseline: 1.4426x; 1.1767x over previous
//
#include <hip/hip_runtime.h>
#include <hip/hip_bf16.h>

#define DIN 256
#define DOUT 128

typedef float f32x4 __attribute__((ext_vector_type(4)));
typedef __bf16 bf16x8 __attribute__((ext_vector_type(8)));
typedef unsigned short u16x8 __attribute__((ext_vector_type(8)));

__device__ __forceinline__ unsigned short f2bf(float f) {
    __bf16 h = (__bf16)f;
    return *(unsigned short*)&h;
}

// ---------------- K0: zero counts ----------------
__global__ void gcn_zero(int* __restrict__ cnt, int N) {
    int i = blockIdx.x * blockDim.x + threadIdx.x;
    if (i < N) cnt[i] = 0;
}

// ---------------- K1: histogram + per-edge rank (ONE atomic per edge) ----------------
__global__ void gcn_count(const int* __restrict__ row, int* __restrict__ cnt,
                          int* __restrict__ rank, int E) {
    int e = blockIdx.x * blockDim.x + threadIdx.x;
    if (e < E) {
        int r = row[e];
        rank[e] = atomicAdd(&cnt[r], 1);
    }
}

// ---------------- exclusive scan of cnt -> row_ptr ----------------
__global__ void gcn_scan_partial(const int* __restrict__ cnt, int* __restrict__ blk, int N) {
    int b = blockIdx.x, t = threadIdx.x;
    int base = b * 1024 + t * 4;
    int s = 0;
#pragma unroll
    for (int k = 0; k < 4; ++k) { int i = base + k; if (i < N) s += cnt[i]; }
    for (int d = 32; d >= 1; d >>= 1) s += __shfl_down(s, d, 64);
    __shared__ int wsum[4];
    int lane = t & 63, wid = t >> 6;
    if (lane == 0) wsum[wid] = s;
    __syncthreads();
    if (t == 0) blk[b] = wsum[0] + wsum[1] + wsum[2] + wsum[3];
}

__global__ void gcn_scan_blk(int* __restrict__ blk, int nblk) {
    if (threadIdx.x == 0) {
        int run = 0;
        for (int i = 0; i < nblk; ++i) { int v = blk[i]; blk[i] = run; run += v; }
    }
}

__global__ void gcn_scan_final(const int* __restrict__ cnt, const int* __restrict__ blk,
                               int* __restrict__ row_ptr, int N, int E) {
    int b = blockIdx.x, t = threadIdx.x;
    int base = b * 1024 + t * 4;
    int v[4]; int s = 0;
#pragma unroll
    for (int k = 0; k < 4; ++k) { int i = base + k; v[k] = (i < N) ? cnt[i] : 0; s += v[k]; }
    int mysum = s;
    int lane = t & 63, wid = t >> 6;
    for (int d = 1; d < 64; d <<= 1) {
        int tt = __shfl_up(s, d, 64);
        if (lane >= d) s += tt;
    }
    __shared__ int wsum[4];
    if (lane == 63) wsum[wid] = s;
    __syncthreads();
    int woff = 0;
    for (int w = 0; w < wid; ++w) woff += wsum[w];
    int excl = blk[b] + woff + (s - mysum);
#pragma unroll
    for (int k = 0; k < 4; ++k) {
        int i = base + k;
        if (i < N) row_ptr[i] = excl;
        excl += v[k];
    }
    if (b == (int)gridDim.x - 1 && t == (int)blockDim.x - 1) row_ptr[N] = E;
}

// ---------------- fill CSR deterministically (no atomics), raw vals ----------------
__global__ void gcn_fill(const int* __restrict__ row, const int* __restrict__ col,
                         const float* __restrict__ vals, const int* __restrict__ row_ptr,
                         const int* __restrict__ rank, int2* __restrict__ csr, int E) {
    int e = blockIdx.x * blockDim.x + threadIdx.x;
    if (e < E) {
        int r = row[e];
        int p = row_ptr[r] + rank[e];
        int2 pk;
        pk.x = col[e];
        pk.y = __float_as_int(vals[e]);
        csr[p] = pk;
    }
}

// ---------------- per-row degree sum -> d^{-1/2} ----------------
__global__ void gcn_degdinv(const int* __restrict__ row_ptr, const int2* __restrict__ csr,
                            float* __restrict__ dinv, int N) {
    int r = blockIdx.x * blockDim.x + threadIdx.x;
    if (r < N) {
        int b = row_ptr[r], e = row_ptr[r + 1];
        float s = 0.f;
        for (int j = b; j < e; ++j) s += __int_as_float(csr[j].y);
        dinv[r] = (s > 0.f) ? rsqrtf(fmaxf(s, 1e-12f)) : 0.f;
    }
}

// ---------------- per-row normalize csr_val *= dinv[r]*dinv[c] ----------------
__global__ void gcn_norm(const int* __restrict__ row_ptr, const float* __restrict__ dinv,
                         int2* __restrict__ csr, int N) {
    int r = blockIdx.x * blockDim.x + threadIdx.x;
    if (r < N) {
        int b = row_ptr[r], e = row_ptr[r + 1];
        float dr = dinv[r];
        for (int j = b; j < e; ++j) {
            int2 p = csr[j];
            csr[j].y = __float_as_int(__int_as_float(p.y) * dr * dinv[p.x]);
        }
    }
}

// ---------------- W f32 [256][128] -> Wt bf16 [128][256] ----------------
__global__ void gcn_wconv(const float* __restrict__ W, unsigned short* __restrict__ Wt) {
    int id = blockIdx.x * blockDim.x + threadIdx.x;  // 32768 total
    int c = id >> 8;       // 0..127
    int k = id & 255;      // 0..255
    Wt[c * 256 + k] = f2bf(W[k * DOUT + c]);
}

// ---------------- support = x @ W + b  (bf16 MFMA, tile 128x128, BK=64) ----------------
__global__ __launch_bounds__(256) void gcn_gemm(const float* __restrict__ x,
                                                const unsigned short* __restrict__ Wt,
                                                const float* __restrict__ bias,
                                                unsigned short* __restrict__ support, int N) {
    __shared__ unsigned short xs[128][72];
    __shared__ unsigned short wl[128][72];

    int t = threadIdx.x;
    int n0 = blockIdx.x * 128;
    int l = t & 63;
    int w = t >> 6;
    int w32 = w * 32;
    int lr = l & 15;
    int lk = (l >> 4) * 8;

    f32x4 acc[2][8] = {};

    int srow = t >> 1;
    int skk = (t & 1) * 32;

    for (int kt = 0; kt < DIN; kt += 64) {
        {
            float4 f[8];
            if (n0 + srow < N) {
                const float4* src = (const float4*)&x[(size_t)(n0 + srow) * DIN + kt + skk];
#pragma unroll
                for (int i = 0; i < 8; ++i) f[i] = src[i];
            } else {
#pragma unroll
                for (int i = 0; i < 8; ++i) f[i] = make_float4(0, 0, 0, 0);
            }
#pragma unroll
            for (int i = 0; i < 4; ++i) {
                u16x8 pk;
                pk[0] = f2bf(f[2 * i].x);     pk[1] = f2bf(f[2 * i].y);
                pk[2] = f2bf(f[2 * i].z);     pk[3] = f2bf(f[2 * i].w);
                pk[4] = f2bf(f[2 * i + 1].x); pk[5] = f2bf(f[2 * i + 1].y);
                pk[6] = f2bf(f[2 * i + 1].z); pk[7] = f2bf(f[2 * i + 1].w);
                *(u16x8*)&xs[srow][skk + 8 * i] = pk;
            }
        }
        {
            const u16x8* src = (const u16x8*)&Wt[(size_t)srow * DIN + kt + skk];
#pragma unroll
            for (int i = 0; i < 4; ++i) *(u16x8*)&wl[srow][skk + 8 * i] = src[i];
        }
        __syncthreads();
#pragma unroll
        for (int ks = 0; ks < 2; ++ks) {
            bf16x8 a[2], b[8];
#pragma unroll
            for (int m = 0; m < 2; ++m)
                a[m] = *(const bf16x8*)&xs[w32 + m * 16 + lr][ks * 32 + lk];
#pragma unroll
            for (int n = 0; n < 8; ++n)
                b[n] = *(const bf16x8*)&wl[n * 16 + lr][ks * 32 + lk];
#pragma unroll
            for (int m = 0; m < 2; ++m)
#pragma unroll
                for (int n = 0; n < 8; ++n)
                    acc[m][n] = __builtin_amdgcn_mfma_f32_16x16x32_bf16(a[m], b[n], acc[m][n], 0, 0, 0);
        }
        __syncthreads();
    }

    float bias_v[8];
#pragma unroll
    for (int n = 0; n < 8; ++n) bias_v[n] = bias[n * 16 + lr];

    int rbase = n0 + w32 + (l >> 4) * 4;
#pragma unroll
    for (int m = 0; m < 2; ++m) {
#pragma unroll
        for (int r = 0; r < 4; ++r) {
            int rowi = rbase + m * 16 + r;
            if (rowi < N) {
                unsigned short* dst = &support[(size_t)rowi * DOUT + lr];
#pragma unroll
                for (int n = 0; n < 8; ++n)
                    dst[n * 16] = f2bf(acc[m][n][r] + bias_v[n]);
            }
        }
    }
}

// ---------------- out[r] = sum_j val[j] * support_bf16[col[j]] ----------------
// one wave per row; edges fetched cooperatively (coalesced) then shfl-broadcast
__global__ __launch_bounds__(256) void gcn_spmm(const int* __restrict__ row_ptr,
                                                const int2* __restrict__ csr,
                                                const unsigned short* __restrict__ support,
                                                float* __restrict__ out, int N) {
    int wid = threadIdx.x >> 6;
    int lane = threadIdx.x & 63;
    int r = blockIdx.x * 4 + wid;
    if (r >= N) return;
    int beg = row_ptr[r], end = row_ptr[r + 1];
    float accx = 0.f, accy = 0.f;

    for (int base = beg; base < end; base += 64) {
        int nj = end - base; if (nj > 64) nj = 64;
        int2 e = make_int2(0, 0);
        if (base + lane < end) e = csr[base + lane];
        for (int j = 0; j < nj; ++j) {
            int c = __shfl(e.x, j, 64);
            float v = __int_as_float(__shfl(e.y, j, 64));
            unsigned int p = *(const unsigned int*)&support[(size_t)c * DOUT + lane * 2];
            accx += v * __uint_as_float(p << 16);
            accy += v * __uint_as_float(p & 0xffff0000u);
        }
    }
    float2 o; o.x = accx; o.y = accy;
    *(float2*)&out[(size_t)r * DOUT + lane * 2] = o;
}

extern "C" void kernel_launch(void* const* d_in, const int* in_sizes, int n_in,
                              void* d_out, int out_size, void* d_ws, size_t ws_size,
                              hipStream_t stream) {
    const float* x    = (const float*)d_in[0];
    const int*   row  = (const int*)d_in[1];
    const int*   col  = (const int*)d_in[2];
    const float* vals = (const float*)d_in[3];
    const float* W    = (const float*)d_in[4];
    const float* bias = (const float*)d_in[5];
    float* out = (float*)d_out;

    int N = in_sizes[0] / DIN;
    int E = in_sizes[1];
    int NBLK = (N + 1023) / 1024;

    char* ws = (char*)d_ws;
    size_t off = 0;
    auto take = [&](size_t bytes) -> char* {
        char* p = ws + off;
        off = (off + bytes + 255) & ~(size_t)255;
        return p;
    };
    float* dinv    = (float*)take((size_t)N * 4);
    int*   cnt     = (int*)take((size_t)N * 4);
    int*   row_ptr = (int*)take((size_t)(N + 1) * 4);
    int*   blk     = (int*)take((size_t)NBLK * 4);
    int*   rank    = (int*)take((size_t)E * 4);
    int2*  csr     = (int2*)take((size_t)E * 8);
    unsigned short* Wt      = (unsigned short*)take((size_t)DIN * DOUT * 2);
    unsigned short* support = (unsigned short*)take((size_t)N * DOUT * 2);
    (void)ws_size;

    int nbN = (N + 255) / 256;
    int nbE = (E + 255) / 256;

    gcn_zero<<<nbN, 256, 0, stream>>>(cnt, N);
    gcn_count<<<nbE, 256, 0, stream>>>(row, cnt, rank, E);
    gcn_scan_partial<<<NBLK, 256, 0, stream>>>(cnt, blk, N);
    gcn_scan_blk<<<1, 64, 0, stream>>>(blk, NBLK);
    gcn_scan_final<<<NBLK, 256, 0, stream>>>(cnt, blk, row_ptr, N, E);
    gcn_fill<<<nbE, 256, 0, stream>>>(row, col, vals, row_ptr, rank, csr, E);
    gcn_degdinv<<<nbN, 256, 0, stream>>>(row_ptr, csr, dinv, N);
    gcn_norm<<<nbN, 256, 0, stream>>>(row_ptr, dinv, csr, N);
    gcn_wconv<<<(DIN * DOUT) / 256, 256, 0, stream>>>(W, Wt);
    gcn_gemm<<<(N + 127) / 128, 256, 0, stream>>>(x, Wt, bias, support, N);
    gcn_spmm<<<(N + 3) / 4, 256, 0, stream>>>(row_ptr, csr, support, out, N);
}

// Round 5
// 390.018 us; speedup vs baseline: 1.6763x; 1.1620x over previous
//
#include <hip/hip_runtime.h>
#include <hip/hip_bf16.h>

#define DIN 256
#define DOUT 128

typedef float f32x4 __attribute__((ext_vector_type(4)));
typedef __bf16 bf16x8 __attribute__((ext_vector_type(8)));
typedef unsigned short u16x8 __attribute__((ext_vector_type(8)));

__device__ __forceinline__ unsigned short f2bf(float f) {
    __bf16 h = (__bf16)f;
    return *(unsigned short*)&h;
}

// ---------------- W f32 [256][128] -> Wt bf16 [128][256] ----------------
__global__ void gcn_wconv(const float* __restrict__ W, unsigned short* __restrict__ Wt) {
    int id = blockIdx.x * blockDim.x + threadIdx.x;  // 32768 total
    int c = id >> 8;       // 0..127
    int k = id & 255;      // 0..255
    Wt[c * 256 + k] = f2bf(W[k * DOUT + c]);
}

// ---------------- fused: [gemm blocks 0..nbG) | [count blocks nbG..nbG+nbE) ----------------
// gemm: support = x @ W + b (bf16 MFMA, tile 128x128, BK=64)
// count: rank[e] = atomicAdd(&cnt[row[e]], 1)   (independent of gemm dataflow)
__global__ __launch_bounds__(256) void gcn_gemm_count(
        const float* __restrict__ x, const unsigned short* __restrict__ Wt,
        const float* __restrict__ bias, unsigned short* __restrict__ support,
        const int* __restrict__ row, int* __restrict__ cnt, int* __restrict__ rank,
        int N, int E, int nbG) {
    __shared__ unsigned short xs[128][72];
    __shared__ unsigned short wl[128][72];

    if ((int)blockIdx.x >= nbG) {
        int e = ((int)blockIdx.x - nbG) * 256 + threadIdx.x;
        if (e < E) rank[e] = atomicAdd(&cnt[row[e]], 1);
        return;
    }

    int t = threadIdx.x;
    int n0 = blockIdx.x * 128;
    int l = t & 63;
    int w = t >> 6;
    int w32 = w * 32;
    int lr = l & 15;
    int lk = (l >> 4) * 8;

    f32x4 acc[2][8] = {};

    int srow = t >> 1;
    int skk = (t & 1) * 32;

    for (int kt = 0; kt < DIN; kt += 64) {
        {
            float4 f[8];
            if (n0 + srow < N) {
                const float4* src = (const float4*)&x[(size_t)(n0 + srow) * DIN + kt + skk];
#pragma unroll
                for (int i = 0; i < 8; ++i) f[i] = src[i];
            } else {
#pragma unroll
                for (int i = 0; i < 8; ++i) f[i] = make_float4(0, 0, 0, 0);
            }
#pragma unroll
            for (int i = 0; i < 4; ++i) {
                u16x8 pk;
                pk[0] = f2bf(f[2 * i].x);     pk[1] = f2bf(f[2 * i].y);
                pk[2] = f2bf(f[2 * i].z);     pk[3] = f2bf(f[2 * i].w);
                pk[4] = f2bf(f[2 * i + 1].x); pk[5] = f2bf(f[2 * i + 1].y);
                pk[6] = f2bf(f[2 * i + 1].z); pk[7] = f2bf(f[2 * i + 1].w);
                *(u16x8*)&xs[srow][skk + 8 * i] = pk;
            }
        }
        {
            const u16x8* src = (const u16x8*)&Wt[(size_t)srow * DIN + kt + skk];
#pragma unroll
            for (int i = 0; i < 4; ++i) *(u16x8*)&wl[srow][skk + 8 * i] = src[i];
        }
        __syncthreads();
#pragma unroll
        for (int ks = 0; ks < 2; ++ks) {
            bf16x8 a[2], b[8];
#pragma unroll
            for (int m = 0; m < 2; ++m)
                a[m] = *(const bf16x8*)&xs[w32 + m * 16 + lr][ks * 32 + lk];
#pragma unroll
            for (int n = 0; n < 8; ++n)
                b[n] = *(const bf16x8*)&wl[n * 16 + lr][ks * 32 + lk];
#pragma unroll
            for (int m = 0; m < 2; ++m)
#pragma unroll
                for (int n = 0; n < 8; ++n)
                    acc[m][n] = __builtin_amdgcn_mfma_f32_16x16x32_bf16(a[m], b[n], acc[m][n], 0, 0, 0);
        }
        __syncthreads();
    }

    float bias_v[8];
#pragma unroll
    for (int n = 0; n < 8; ++n) bias_v[n] = bias[n * 16 + lr];

    int rbase = n0 + w32 + (l >> 4) * 4;
#pragma unroll
    for (int m = 0; m < 2; ++m) {
#pragma unroll
        for (int r = 0; r < 4; ++r) {
            int rowi = rbase + m * 16 + r;
            if (rowi < N) {
                unsigned short* dst = &support[(size_t)rowi * DOUT + lr];
#pragma unroll
                for (int n = 0; n < 8; ++n)
                    dst[n * 16] = f2bf(acc[m][n][r] + bias_v[n]);
            }
        }
    }
}

// ---------------- exclusive scan of cnt -> row_ptr ----------------
__global__ void gcn_scan_partial(const int* __restrict__ cnt, int* __restrict__ blk, int N) {
    int b = blockIdx.x, t = threadIdx.x;
    int base = b * 1024 + t * 4;
    int s = 0;
#pragma unroll
    for (int k = 0; k < 4; ++k) { int i = base + k; if (i < N) s += cnt[i]; }
    for (int d = 32; d >= 1; d >>= 1) s += __shfl_down(s, d, 64);
    __shared__ int wsum[4];
    int lane = t & 63, wid = t >> 6;
    if (lane == 0) wsum[wid] = s;
    __syncthreads();
    if (t == 0) blk[b] = wsum[0] + wsum[1] + wsum[2] + wsum[3];
}

__global__ void gcn_scan_blk(int* __restrict__ blk, int nblk) {
    if (threadIdx.x == 0) {
        int run = 0;
        for (int i = 0; i < nblk; ++i) { int v = blk[i]; blk[i] = run; run += v; }
    }
}

__global__ void gcn_scan_final(const int* __restrict__ cnt, const int* __restrict__ blk,
                               int* __restrict__ row_ptr, int N, int E) {
    int b = blockIdx.x, t = threadIdx.x;
    int base = b * 1024 + t * 4;
    int v[4]; int s = 0;
#pragma unroll
    for (int k = 0; k < 4; ++k) { int i = base + k; v[k] = (i < N) ? cnt[i] : 0; s += v[k]; }
    int mysum = s;
    int lane = t & 63, wid = t >> 6;
    for (int d = 1; d < 64; d <<= 1) {
        int tt = __shfl_up(s, d, 64);
        if (lane >= d) s += tt;
    }
    __shared__ int wsum[4];
    if (lane == 63) wsum[wid] = s;
    __syncthreads();
    int woff = 0;
    for (int w = 0; w < wid; ++w) woff += wsum[w];
    int excl = blk[b] + woff + (s - mysum);
#pragma unroll
    for (int k = 0; k < 4; ++k) {
        int i = base + k;
        if (i < N) row_ptr[i] = excl;
        excl += v[k];
    }
    if (b == (int)gridDim.x - 1 && t == (int)blockDim.x - 1) row_ptr[N] = E;
}

// ---------------- fill CSR deterministically (no atomics), raw vals ----------------
__global__ void gcn_fill(const int* __restrict__ row, const int* __restrict__ col,
                         const float* __restrict__ vals, const int* __restrict__ row_ptr,
                         const int* __restrict__ rank, int2* __restrict__ csr, int E) {
    int e = blockIdx.x * blockDim.x + threadIdx.x;
    if (e < E) {
        int r = row[e];
        int p = row_ptr[r] + rank[e];
        int2 pk;
        pk.x = col[e];
        pk.y = __float_as_int(vals[e]);
        csr[p] = pk;
    }
}

// ---------------- per-row degree sum -> d^{-1/2}  (16 lanes per row, coalesced) ----------------
__global__ __launch_bounds__(256) void gcn_degdinv(const int* __restrict__ row_ptr,
                                                   const int2* __restrict__ csr,
                                                   float* __restrict__ dinv, int N) {
    int t = threadIdx.x;
    int fl = t & 15;
    int r = blockIdx.x * 16 + (t >> 4);
    if (r >= N) return;
    int beg = row_ptr[r], end = row_ptr[r + 1];
    float s = 0.f;
    for (int j = beg + fl; j < end; j += 16) s += __int_as_float(csr[j].y);
    s += __shfl_xor(s, 1, 64);
    s += __shfl_xor(s, 2, 64);
    s += __shfl_xor(s, 4, 64);
    s += __shfl_xor(s, 8, 64);
    if (fl == 0) dinv[r] = (s > 0.f) ? rsqrtf(fmaxf(s, 1e-12f)) : 0.f;
}

// ---------------- normalize csr_val *= dinv[r]*dinv[c]  (16 lanes per row) ----------------
__global__ __launch_bounds__(256) void gcn_norm(const int* __restrict__ row_ptr,
                                                const float* __restrict__ dinv,
                                                int2* __restrict__ csr, int N) {
    int t = threadIdx.x;
    int fl = t & 15;
    int r = blockIdx.x * 16 + (t >> 4);
    if (r >= N) return;
    int beg = row_ptr[r], end = row_ptr[r + 1];
    float dr = dinv[r];
    for (int j = beg + fl; j < end; j += 16) {
        int2 p = csr[j];
        csr[j].y = __float_as_int(__int_as_float(p.y) * dr * dinv[p.x]);
    }
}

// ---------------- out[r] = sum_j val[j] * support_bf16[col[j]] ----------------
// one wave per row; 4 edges concurrently, 16 lanes x 16B per edge
__global__ __launch_bounds__(256) void gcn_spmm(const int* __restrict__ row_ptr,
                                                const int2* __restrict__ csr,
                                                const unsigned short* __restrict__ support,
                                                float* __restrict__ out, int N) {
    int wid = threadIdx.x >> 6;
    int lane = threadIdx.x & 63;
    int r = blockIdx.x * 4 + wid;
    if (r >= N) return;
    int beg = row_ptr[r], end = row_ptr[r + 1];
    int g = lane >> 4;        // edge slot 0..3
    int fl = lane & 15;       // feature block: features fl*8 .. fl*8+7
    float acc[8] = {};

    for (int base = beg; base < end; base += 64) {
        int nj = end - base; if (nj > 64) nj = 64;
        int2 e = make_int2(0, 0);
        if (base + lane < end) e = csr[base + lane];
        int nchunk = (nj + 3) >> 2;
        for (int q = 0; q < nchunk; ++q) {
            int idx = q * 4 + g;
            int c = __shfl(e.x, idx, 64);
            float v = __int_as_float(__shfl(e.y, idx, 64));
            if (idx < nj) {
                uint4 p = *(const uint4*)&support[(size_t)c * DOUT + fl * 8];
                acc[0] += v * __uint_as_float(p.x << 16);
                acc[1] += v * __uint_as_float(p.x & 0xffff0000u);
                acc[2] += v * __uint_as_float(p.y << 16);
                acc[3] += v * __uint_as_float(p.y & 0xffff0000u);
                acc[4] += v * __uint_as_float(p.z << 16);
                acc[5] += v * __uint_as_float(p.z & 0xffff0000u);
                acc[6] += v * __uint_as_float(p.w << 16);
                acc[7] += v * __uint_as_float(p.w & 0xffff0000u);
            }
        }
    }
#pragma unroll
    for (int i = 0; i < 8; ++i) {
        acc[i] += __shfl_xor(acc[i], 16, 64);
        acc[i] += __shfl_xor(acc[i], 32, 64);
    }
    if (g == 0) {
        float4 o0, o1;
        o0.x = acc[0]; o0.y = acc[1]; o0.z = acc[2]; o0.w = acc[3];
        o1.x = acc[4]; o1.y = acc[5]; o1.z = acc[6]; o1.w = acc[7];
        float* dst = &out[(size_t)r * DOUT + fl * 8];
        *(float4*)dst = o0;
        *(float4*)(dst + 4) = o1;
    }
}

extern "C" void kernel_launch(void* const* d_in, const int* in_sizes, int n_in,
                              void* d_out, int out_size, void* d_ws, size_t ws_size,
                              hipStream_t stream) {
    const float* x    = (const float*)d_in[0];
    const int*   row  = (const int*)d_in[1];
    const int*   col  = (const int*)d_in[2];
    const float* vals = (const float*)d_in[3];
    const float* W    = (const float*)d_in[4];
    const float* bias = (const float*)d_in[5];
    float* out = (float*)d_out;

    int N = in_sizes[0] / DIN;
    int E = in_sizes[1];
    int NBLK = (N + 1023) / 1024;

    char* ws = (char*)d_ws;
    size_t off = 0;
    auto take = [&](size_t bytes) -> char* {
        char* p = ws + off;
        off = (off + bytes + 255) & ~(size_t)255;
        return p;
    };
    float* dinv    = (float*)take((size_t)N * 4);
    int*   cnt     = (int*)take((size_t)N * 4);
    int*   row_ptr = (int*)take((size_t)(N + 1) * 4);
    int*   blk     = (int*)take((size_t)NBLK * 4);
    int*   rank    = (int*)take((size_t)E * 4);
    int2*  csr     = (int2*)take((size_t)E * 8);
    unsigned short* Wt      = (unsigned short*)take((size_t)DIN * DOUT * 2);
    unsigned short* support = (unsigned short*)take((size_t)N * DOUT * 2);
    (void)ws_size;

    int nbE = (E + 255) / 256;
    int nbG = (N + 127) / 128;

    hipMemsetAsync(cnt, 0, (size_t)N * 4, stream);
    gcn_wconv<<<(DIN * DOUT) / 256, 256, 0, stream>>>(W, Wt);
    gcn_gemm_count<<<nbG + nbE, 256, 0, stream>>>(x, Wt, bias, support, row, cnt, rank, N, E, nbG);
    gcn_scan_partial<<<NBLK, 256, 0, stream>>>(cnt, blk, N);
    gcn_scan_blk<<<1, 64, 0, stream>>>(blk, NBLK);
    gcn_scan_final<<<NBLK, 256, 0, stream>>>(cnt, blk, row_ptr, N, E);
    gcn_fill<<<nbE, 256, 0, stream>>>(row, col, vals, row_ptr, rank, csr, E);
    gcn_degdinv<<<(N + 15) / 16, 256, 0, stream>>>(row_ptr, csr, dinv, N);
    gcn_norm<<<(N + 15) / 16, 256, 0, stream>>>(row_ptr, dinv, csr, N);
    gcn_spmm<<<(N + 3) / 4, 256, 0, stream>>>(row_ptr, csr, support, out, N);
}

// Round 6
// 376.736 us; speedup vs baseline: 1.7354x; 1.0353x over previous
//
#include <hip/hip_runtime.h>
#include <hip/hip_bf16.h>

#define DIN 256
#define DOUT 128

typedef float f32x4 __attribute__((ext_vector_type(4)));
typedef __bf16 bf16x8 __attribute__((ext_vector_type(8)));
typedef unsigned short u16x8 __attribute__((ext_vector_type(8)));

__device__ __forceinline__ unsigned short f2bf(float f) {
    __bf16 h = (__bf16)f;
    return *(unsigned short*)&h;
}

// ---------------- W f32 [256][128] -> Wt bf16 [128][256] ----------------
__global__ void gcn_wconv(const float* __restrict__ W, unsigned short* __restrict__ Wt) {
    int id = blockIdx.x * blockDim.x + threadIdx.x;  // 32768 total
    int c = id >> 8;       // 0..127
    int k = id & 255;      // 0..255
    Wt[c * 256 + k] = f2bf(W[k * DOUT + c]);
}

// ---------------- fused: [gemm blocks 0..nbG) | [count blocks nbG..nbG+nbE) ----------------
__global__ __launch_bounds__(256) void gcn_gemm_count(
        const float* __restrict__ x, const unsigned short* __restrict__ Wt,
        const float* __restrict__ bias, unsigned short* __restrict__ support,
        const int* __restrict__ row, int* __restrict__ cnt, int* __restrict__ rank,
        int N, int E, int nbG) {
    __shared__ unsigned short xs[128][72];
    __shared__ unsigned short wl[128][72];

    if ((int)blockIdx.x >= nbG) {
        int e = ((int)blockIdx.x - nbG) * 256 + threadIdx.x;
        if (e < E) rank[e] = atomicAdd(&cnt[row[e]], 1);
        return;
    }

    int t = threadIdx.x;
    int n0 = blockIdx.x * 128;
    int l = t & 63;
    int w = t >> 6;
    int w32 = w * 32;
    int lr = l & 15;
    int lk = (l >> 4) * 8;

    f32x4 acc[2][8] = {};

    int srow = t >> 1;
    int skk = (t & 1) * 32;

    for (int kt = 0; kt < DIN; kt += 64) {
        {
            float4 f[8];
            if (n0 + srow < N) {
                const float4* src = (const float4*)&x[(size_t)(n0 + srow) * DIN + kt + skk];
#pragma unroll
                for (int i = 0; i < 8; ++i) f[i] = src[i];
            } else {
#pragma unroll
                for (int i = 0; i < 8; ++i) f[i] = make_float4(0, 0, 0, 0);
            }
#pragma unroll
            for (int i = 0; i < 4; ++i) {
                u16x8 pk;
                pk[0] = f2bf(f[2 * i].x);     pk[1] = f2bf(f[2 * i].y);
                pk[2] = f2bf(f[2 * i].z);     pk[3] = f2bf(f[2 * i].w);
                pk[4] = f2bf(f[2 * i + 1].x); pk[5] = f2bf(f[2 * i + 1].y);
                pk[6] = f2bf(f[2 * i + 1].z); pk[7] = f2bf(f[2 * i + 1].w);
                *(u16x8*)&xs[srow][skk + 8 * i] = pk;
            }
        }
        {
            const u16x8* src = (const u16x8*)&Wt[(size_t)srow * DIN + kt + skk];
#pragma unroll
            for (int i = 0; i < 4; ++i) *(u16x8*)&wl[srow][skk + 8 * i] = src[i];
        }
        __syncthreads();
#pragma unroll
        for (int ks = 0; ks < 2; ++ks) {
            bf16x8 a[2], b[8];
#pragma unroll
            for (int m = 0; m < 2; ++m)
                a[m] = *(const bf16x8*)&xs[w32 + m * 16 + lr][ks * 32 + lk];
#pragma unroll
            for (int n = 0; n < 8; ++n)
                b[n] = *(const bf16x8*)&wl[n * 16 + lr][ks * 32 + lk];
#pragma unroll
            for (int m = 0; m < 2; ++m)
#pragma unroll
                for (int n = 0; n < 8; ++n)
                    acc[m][n] = __builtin_amdgcn_mfma_f32_16x16x32_bf16(a[m], b[n], acc[m][n], 0, 0, 0);
        }
        __syncthreads();
    }

    float bias_v[8];
#pragma unroll
    for (int n = 0; n < 8; ++n) bias_v[n] = bias[n * 16 + lr];

    int rbase = n0 + w32 + (l >> 4) * 4;
#pragma unroll
    for (int m = 0; m < 2; ++m) {
#pragma unroll
        for (int r = 0; r < 4; ++r) {
            int rowi = rbase + m * 16 + r;
            if (rowi < N) {
                unsigned short* dst = &support[(size_t)rowi * DOUT + lr];
#pragma unroll
                for (int n = 0; n < 8; ++n)
                    dst[n * 16] = f2bf(acc[m][n][r] + bias_v[n]);
            }
        }
    }
}

// ---------------- exclusive scan of cnt -> row_ptr ----------------
__global__ void gcn_scan_partial(const int* __restrict__ cnt, int* __restrict__ blk, int N) {
    int b = blockIdx.x, t = threadIdx.x;
    int base = b * 1024 + t * 4;
    int s = 0;
#pragma unroll
    for (int k = 0; k < 4; ++k) { int i = base + k; if (i < N) s += cnt[i]; }
    for (int d = 32; d >= 1; d >>= 1) s += __shfl_down(s, d, 64);
    __shared__ int wsum[4];
    int lane = t & 63, wid = t >> 6;
    if (lane == 0) wsum[wid] = s;
    __syncthreads();
    if (t == 0) blk[b] = wsum[0] + wsum[1] + wsum[2] + wsum[3];
}

__global__ void gcn_scan_blk(int* __restrict__ blk, int nblk) {
    if (threadIdx.x == 0) {
        int run = 0;
        for (int i = 0; i < nblk; ++i) { int v = blk[i]; blk[i] = run; run += v; }
    }
}

__global__ void gcn_scan_final(const int* __restrict__ cnt, const int* __restrict__ blk,
                               int* __restrict__ row_ptr, int N, int E) {
    int b = blockIdx.x, t = threadIdx.x;
    int base = b * 1024 + t * 4;
    int v[4]; int s = 0;
#pragma unroll
    for (int k = 0; k < 4; ++k) { int i = base + k; v[k] = (i < N) ? cnt[i] : 0; s += v[k]; }
    int mysum = s;
    int lane = t & 63, wid = t >> 6;
    for (int d = 1; d < 64; d <<= 1) {
        int tt = __shfl_up(s, d, 64);
        if (lane >= d) s += tt;
    }
    __shared__ int wsum[4];
    if (lane == 63) wsum[wid] = s;
    __syncthreads();
    int woff = 0;
    for (int w = 0; w < wid; ++w) woff += wsum[w];
    int excl = blk[b] + woff + (s - mysum);
#pragma unroll
    for (int k = 0; k < 4; ++k) {
        int i = base + k;
        if (i < N) row_ptr[i] = excl;
        excl += v[k];
    }
    if (b == (int)gridDim.x - 1 && t == (int)blockDim.x - 1) row_ptr[N] = E;
}

// ---------------- fill CSR deterministically (no atomics), raw vals ----------------
__global__ void gcn_fill(const int* __restrict__ row, const int* __restrict__ col,
                         const float* __restrict__ vals, const int* __restrict__ row_ptr,
                         const int* __restrict__ rank, int2* __restrict__ csr, int E) {
    int e = blockIdx.x * blockDim.x + threadIdx.x;
    if (e < E) {
        int r = row[e];
        int p = row_ptr[r] + rank[e];
        int2 pk;
        pk.x = col[e];
        pk.y = __float_as_int(vals[e]);
        csr[p] = pk;
    }
}

// ---------------- per-row degree sum (raw vals) -> d^{-1/2} ----------------
__global__ __launch_bounds__(256) void gcn_degdinv(const int* __restrict__ row_ptr,
                                                   const int2* __restrict__ csr,
                                                   float* __restrict__ dinv, int N) {
    int t = threadIdx.x;
    int fl = t & 15;
    int r = blockIdx.x * 16 + (t >> 4);
    if (r >= N) return;
    int beg = row_ptr[r], end = row_ptr[r + 1];
    float s = 0.f;
    for (int j = beg + fl; j < end; j += 16) s += __int_as_float(csr[j].y);
    s += __shfl_xor(s, 1, 64);
    s += __shfl_xor(s, 2, 64);
    s += __shfl_xor(s, 4, 64);
    s += __shfl_xor(s, 8, 64);
    if (fl == 0) dinv[r] = (s > 0.f) ? rsqrtf(fmaxf(s, 1e-12f)) : 0.f;
}

// ---------------- out[r] = dinv[r] * sum_j rawval_j*dinv[c_j] * support[c_j] ----------------
// one wave per row; 8 edges concurrently (two per 16-lane group), norm fused
__global__ __launch_bounds__(256) void gcn_spmm(const int* __restrict__ row_ptr,
                                                const int2* __restrict__ csr,
                                                const float* __restrict__ dinv,
                                                const unsigned short* __restrict__ support,
                                                float* __restrict__ out, int N) {
    int wid = threadIdx.x >> 6;
    int lane = threadIdx.x & 63;
    int r = blockIdx.x * 4 + wid;
    if (r >= N) return;
    int beg = row_ptr[r], end = row_ptr[r + 1];
    int g = lane >> 4;        // edge slot 0..3
    int fl = lane & 15;       // feature block: features fl*8 .. fl*8+7
    float acc[8] = {};

    for (int base = beg; base < end; base += 64) {
        int nj = end - base; if (nj > 64) nj = 64;
        int2 e = make_int2(0, 0);
        if (base + lane < end) e = csr[base + lane];
        int nchunk = (nj + 7) >> 3;
        for (int q = 0; q < nchunk; ++q) {
            int ia = q * 8 + g;
            int ib = ia + 4;
            int ca = __shfl(e.x, ia, 64);
            float va = __int_as_float(__shfl(e.y, ia, 64));
            int cb = __shfl(e.x, ib, 64);
            float vb = __int_as_float(__shfl(e.y, ib, 64));
            bool pa = ia < nj, pb = ib < nj;
            uint4 sa = make_uint4(0, 0, 0, 0), sb = make_uint4(0, 0, 0, 0);
            float da = 0.f, db = 0.f;
            if (pa) { da = dinv[ca]; sa = *(const uint4*)&support[(size_t)ca * DOUT + fl * 8]; }
            if (pb) { db = dinv[cb]; sb = *(const uint4*)&support[(size_t)cb * DOUT + fl * 8]; }
            va *= da; vb *= db;
            acc[0] += va * __uint_as_float(sa.x << 16);
            acc[1] += va * __uint_as_float(sa.x & 0xffff0000u);
            acc[2] += va * __uint_as_float(sa.y << 16);
            acc[3] += va * __uint_as_float(sa.y & 0xffff0000u);
            acc[4] += va * __uint_as_float(sa.z << 16);
            acc[5] += va * __uint_as_float(sa.z & 0xffff0000u);
            acc[6] += va * __uint_as_float(sa.w << 16);
            acc[7] += va * __uint_as_float(sa.w & 0xffff0000u);
            acc[0] += vb * __uint_as_float(sb.x << 16);
            acc[1] += vb * __uint_as_float(sb.x & 0xffff0000u);
            acc[2] += vb * __uint_as_float(sb.y << 16);
            acc[3] += vb * __uint_as_float(sb.y & 0xffff0000u);
            acc[4] += vb * __uint_as_float(sb.z << 16);
            acc[5] += vb * __uint_as_float(sb.z & 0xffff0000u);
            acc[6] += vb * __uint_as_float(sb.w << 16);
            acc[7] += vb * __uint_as_float(sb.w & 0xffff0000u);
        }
    }
#pragma unroll
    for (int i = 0; i < 8; ++i) {
        acc[i] += __shfl_xor(acc[i], 16, 64);
        acc[i] += __shfl_xor(acc[i], 32, 64);
    }
    if (g == 0) {
        float dr = dinv[r];
        float4 o0, o1;
        o0.x = acc[0] * dr; o0.y = acc[1] * dr; o0.z = acc[2] * dr; o0.w = acc[3] * dr;
        o1.x = acc[4] * dr; o1.y = acc[5] * dr; o1.z = acc[6] * dr; o1.w = acc[7] * dr;
        float* dst = &out[(size_t)r * DOUT + fl * 8];
        *(float4*)dst = o0;
        *(float4*)(dst + 4) = o1;
    }
}

extern "C" void kernel_launch(void* const* d_in, const int* in_sizes, int n_in,
                              void* d_out, int out_size, void* d_ws, size_t ws_size,
                              hipStream_t stream) {
    const float* x    = (const float*)d_in[0];
    const int*   row  = (const int*)d_in[1];
    const int*   col  = (const int*)d_in[2];
    const float* vals = (const float*)d_in[3];
    const float* W    = (const float*)d_in[4];
    const float* bias = (const float*)d_in[5];
    float* out = (float*)d_out;

    int N = in_sizes[0] / DIN;
    int E = in_sizes[1];
    int NBLK = (N + 1023) / 1024;

    char* ws = (char*)d_ws;
    size_t off = 0;
    auto take = [&](size_t bytes) -> char* {
        char* p = ws + off;
        off = (off + bytes + 255) & ~(size_t)255;
        return p;
    };
    float* dinv    = (float*)take((size_t)N * 4);
    int*   cnt     = (int*)take((size_t)N * 4);
    int*   row_ptr = (int*)take((size_t)(N + 1) * 4);
    int*   blk     = (int*)take((size_t)NBLK * 4);
    int*   rank    = (int*)take((size_t)E * 4);
    int2*  csr     = (int2*)take((size_t)E * 8);
    unsigned short* Wt      = (unsigned short*)take((size_t)DIN * DOUT * 2);
    unsigned short* support = (unsigned short*)take((size_t)N * DOUT * 2);
    (void)ws_size;

    int nbE = (E + 255) / 256;
    int nbG = (N + 127) / 128;

    hipMemsetAsync(cnt, 0, (size_t)N * 4, stream);
    gcn_wconv<<<(DIN * DOUT) / 256, 256, 0, stream>>>(W, Wt);
    gcn_gemm_count<<<nbG + nbE, 256, 0, stream>>>(x, Wt, bias, support, row, cnt, rank, N, E, nbG);
    gcn_scan_partial<<<NBLK, 256, 0, stream>>>(cnt, blk, N);
    gcn_scan_blk<<<1, 64, 0, stream>>>(blk, NBLK);
    gcn_scan_final<<<NBLK, 256, 0, stream>>>(cnt, blk, row_ptr, N, E);
    gcn_fill<<<nbE, 256, 0, stream>>>(row, col, vals, row_ptr, rank, csr, E);
    gcn_degdinv<<<(N + 15) / 16, 256, 0, stream>>>(row_ptr, csr, dinv, N);
    gcn_spmm<<<(N + 3) / 4, 256, 0, stream>>>(row_ptr, csr, dinv, support, out, N);
}